// Round 14
// baseline (415.063 us; speedup 1.0000x reference)
//
#include <hip/hip_runtime.h>

#define NROW 6
#define NCOL 6
#define BATCH 1024
#define NSITE 36

typedef float f32x2 __attribute__((ext_vector_type(2)));

// LDS bank-conflict swizzle: XOR dword-addr bits [4:2] with bits [7:5].
// Preserves bits [1:0]; constant within any aligned 4-dword window; SWZ(0)==0.
__device__ __forceinline__ int SWZ(int a) { return a ^ (((a >> 5) & 7) << 2); }

// Wave-uniform scalar-memory pointers: address_space(4) = AMDGPU constant.
// Scalar/vector primitive loads at uniform addresses -> s_load (SMEM pipe,
// one fetch per wave). R12 proved this path: 534 -> 372 us.
typedef const float __attribute__((address_space(4))) * fcp;
typedef const f32x2 __attribute__((address_space(4))) * f2cp;

// Pre-transpose T[site][spin][u=x][r=gp][d=z][l=g] into PAIR-INTERLEAVED
// Tm[(site*2+spin)*256 + o2*32 + i*2 + p]  where o = 2*o2+p = gp*4+z and
// i = g*4+x.  Each (o2,i) float2 = (M[2o2][i], M[2o2+1][i]) is an aligned
// SGPR pair -> v_pk_fma_f32 operand (2 MACs/instruction).
__global__ void peps_reorder_kernel(const float* __restrict__ T,
                                    float* __restrict__ Tm)
{
    int idx = blockIdx.x * 256 + threadIdx.x;   // [0, 18432)
    if (idx >= NSITE * 2 * 256) return;
    int p  = idx & 1;
    int i  = (idx >> 1) & 15;
    int o2 = (idx >> 5) & 7;
    int sp = (idx >> 8) & 1;
    int st = idx >> 9;
    int o = 2 * o2 + p, gp = o >> 2, z = o & 3, g = i >> 2, x = i & 3;
    Tm[idx] = T[st * 512 + sp * 256 + x * 64 + gp * 16 + z * 4 + g];
}

// Fixed-slot in-place contraction (verified R8..R13 algebra): state index =
// g*4096 + sum_j slot_j*4^j; step (row,c) reads up-bond x from slot c and
// writes down-bond z back into the same slot. ONE barrier/step. State in LDS
// (64 KB, swizzled). M via AS(4) s_load. 1024 threads: 2 blocks/CU x 16
// waves = 32 waves/CU (R13: occupancy fix, 77% VALUBusy).
// R13 binder: VALU issue (286 us issued vs 62 us FMA wall). This round:
// (a) v_pk_fma_f32 via float2 accumulators + pair-interleaved M (halves FMA
// issue); (b) address CSE: read-addr set == write-addr set, 4 SWZ total.
__global__ __launch_bounds__(1024, 8)
void peps_amp_kernel(const int* __restrict__ X, const float* __restrict__ Tm,
                     float* __restrict__ out)
{
    __shared__ float W[16384];   // 65536 B exactly (4^7 fixed-slot state)

    const int b = blockIdx.x;
    const int t = threadIdx.x;   // == this thread's spectator index m
    const int* xrow = X + b * NSITE;

    // PHYS=2: pack the 36 spins into one scalar 64-bit mask (SGPR-resident
    // so every Tm address below is provably wave-uniform).
    unsigned long long sm = 0ull;
    const int4* xp = (const int4*)xrow;
    #pragma unroll
    for (int k = 0; k < 9; ++k) {
        int4 v = xp[k];
        sm |= ((unsigned long long)(v.x & 1)) << (4 * k + 0);
        sm |= ((unsigned long long)(v.y & 1)) << (4 * k + 1);
        sm |= ((unsigned long long)(v.z & 1)) << (4 * k + 2);
        sm |= ((unsigned long long)(v.w & 1)) << (4 * k + 3);
    }
    {
        unsigned lo = __builtin_amdgcn_readfirstlane((int)(sm & 0xffffffffull));
        unsigned hi = __builtin_amdgcn_readfirstlane((int)(sm >> 32));
        sm = ((unsigned long long)hi << 32) | lo;
    }

    if (t == 0) W[0] = 1.0f;     // seed (SWZ(0)==0); covered by step-0 barrier

    int step = 0;
    for (int row = 0; row < NROW; ++row) {
        const int xs = (row == 0) ? 1 : 4;          // up-bond size
        const int zs = (row == NROW - 1) ? 1 : 4;   // down-bond size
        for (int c = 0; c < NCOL; ++c, ++step) {
            const int gin  = (c == 0) ? 1 : 4;
            const int gout = (c == NCOL - 1) ? 1 : 4;
            const int lowb  = (zs == 4) ? 2 * c : 0;
            const int highb = (xs == 4) ? 2 * (5 - c) : 0;
            const int scount = 1 << (lowb + highb);
            const int p4c = 1 << (2 * c);
            const int lowmask = (1 << lowb) - 1;
            const int mr0 = ((t >> lowb) << (2 * c + 2)) | (t & lowmask);
            const bool act = (t < scount);

            // uniform scalars: spin bit + M base (SMEM float2 pointer)
            const int spin = (int)((sm >> step) & 1ull);
            const f2cp Ms2 = (f2cp)(unsigned long long)
                (const void*)(Tm + (size_t)(step * 2 + spin) * 256);

            __syncthreads();     // the ONLY barrier per step

            // ---- shared read/write LDS addresses (x and z span slot c) ----
            int A[4];
            if (c == 0) {
                A[0] = SWZ(4 * t);          // aligned quad base (x/z low digit)
            } else {
                #pragma unroll
                for (int d = 0; d < 4; ++d) A[d] = SWZ(d * p4c + mr0);
            }

            // ---- read phase (divergent, thread-private addresses) ----
            float in[16];
            if (act) {
                if (c == 0) {
                    #pragma unroll
                    for (int g = 0; g < 4; ++g) if (g < gin) {
                        float4 r0 = *(const float4*)&W[A[0] + g * 4096];
                        in[g*4+0]=r0.x; in[g*4+1]=r0.y;
                        in[g*4+2]=r0.z; in[g*4+3]=r0.w;
                    }
                } else {
                    #pragma unroll
                    for (int g = 0; g < 4; ++g) if (g < gin) {
                        #pragma unroll
                        for (int x = 0; x < 4; ++x) if (x < xs) {
                            in[g*4+x] = W[A[x] + g * 4096];
                        }
                    }
                }
            }

            // ---- compute: 8 packed accumulators, M pairs from SMEM ----
            const int no2 = (gout == 1) ? 2 : 8;    // active output pairs
            f32x2 acc2[8];
            #pragma unroll
            for (int o2 = 0; o2 < 8; ++o2) acc2[o2] = (f32x2)(0.f);
            #pragma unroll
            for (int g = 0; g < 4; ++g) if (g < gin) {
                #pragma unroll
                for (int x = 0; x < 4; ++x) if (x < xs) {
                    // uniform s_loads (outside the act guard)
                    f32x2 m2[8];
                    #pragma unroll
                    for (int o2 = 0; o2 < 8; ++o2) if (o2 < no2)
                        m2[o2] = Ms2[o2 * 16 + (g * 4 + x)];
                    if (act) {
                        const float v = in[g*4+x];
                        const f32x2 vv = {v, v};
                        #pragma unroll
                        for (int o2 = 0; o2 < 8; ++o2) if (o2 < no2)
                            acc2[o2] += m2[o2] * vv;   // -> v_pk_fma_f32
                    }
                }
            }

            // ---- write phase (same addresses A[], in-place) ----
            if (act) {
                if (c == 0 && zs == 4) {
                    #pragma unroll
                    for (int gp = 0; gp < 4; ++gp) if (gp < gout) {
                        *(float4*)&W[A[0] + gp * 4096] = make_float4(
                            acc2[2*gp][0], acc2[2*gp][1],
                            acc2[2*gp+1][0], acc2[2*gp+1][1]);
                    }
                } else if (zs == 4) {
                    #pragma unroll
                    for (int gp = 0; gp < 4; ++gp) if (gp < gout) {
                        #pragma unroll
                        for (int z = 0; z < 4; ++z) {
                            W[A[z] + gp * 4096] = acc2[2*gp + (z >> 1)][z & 1];
                        }
                    }
                } else {    // zs == 1: only z = 0 survives (o = 4*gp, even)
                    #pragma unroll
                    for (int gp = 0; gp < 4; ++gp) if (gp < gout) {
                        W[A[0] + gp * 4096] = acc2[2*gp][0];
                    }
                }
            }
        }
    }
    __syncthreads();
    // after (5,5): only g'=0, z=0, m=0 live -> the amplitude sits at W[0]
    if (t == 0) out[b] = W[0];
}

extern "C" void kernel_launch(void* const* d_in, const int* in_sizes, int n_in,
                              void* d_out, int out_size, void* d_ws, size_t ws_size,
                              hipStream_t stream) {
    const int*   X  = (const int*)d_in[0];     // x: [1024, 36] int32
    const float* Tg = (const float*)d_in[1];   // T: [6,6,2,4,4,4,4] fp32
    float* out = (float*)d_out;                // reference output: float32
    float* Tm  = (float*)d_ws;                 // 73,728 B scratch
    (void)in_sizes; (void)n_in; (void)ws_size; (void)out_size;
    peps_reorder_kernel<<<dim3(72), dim3(256), 0, stream>>>(Tg, Tm);
    peps_amp_kernel<<<dim3(BATCH), dim3(1024), 0, stream>>>(X, Tm, out);
}

// Round 15
// 378.665 us; speedup vs baseline: 1.0961x; 1.0961x over previous
//
#include <hip/hip_runtime.h>

#define NROW 6
#define NCOL 6
#define BATCH 1024
#define NSITE 36

// LDS bank-conflict swizzle: XOR dword-addr bits [4:2] with bits [7:5].
// Preserves bits [1:0]; constant within any aligned 4-dword window; SWZ(0)==0.
__device__ __forceinline__ int SWZ(int a) { return a ^ (((a >> 5) & 7) << 2); }

// Wave-uniform scalar-memory pointer: address_space(4) = AMDGPU constant.
// Scalar float loads at uniform literal offsets merge into s_load_dwordx4/x16:
// ONE SMEM fetch per wave (R12 proved: 534 -> 372 us). Keep rows CONTIGUOUS
// (R14's pair-interleave fragmented the merge: 16 dwordx16 -> 128 dwordx2).
typedef const float __attribute__((address_space(4))) * fcp;

// Pre-transpose T[site][spin][u=x][r=gp][d=z][l=g] into
// Tm[(site*2+spin)*256 + (gp*4+z)*16 + (g*4+x)]  (73,728 B in d_ws).
__global__ void peps_reorder_kernel(const float* __restrict__ T,
                                    float* __restrict__ Tm)
{
    int idx = blockIdx.x * 256 + threadIdx.x;   // [0, 18432)
    if (idx >= NSITE * 2 * 256) return;
    int i  = idx & 15;          // i = g*4 + x
    int o  = (idx >> 4) & 15;   // o = gp*4 + z
    int sp = (idx >> 8) & 1;
    int st = idx >> 9;
    int g = i >> 2, x = i & 3, gp = o >> 2, z = o & 3;
    Tm[idx] = T[st * 512 + sp * 256 + x * 64 + gp * 16 + z * 4 + g];
}

// Fixed-slot in-place contraction (verified R8..R13 algebra): state index =
// g*4096 + sum_j slot_j*4^j; step (row,c) reads up-bond x from slot c and
// writes down-bond z back into the same slot. ONE barrier/step. State in LDS
// (64 KB, swizzled). M via AS(4) s_load (dwordx16 rows). 1024 threads:
// 2 blocks/CU x 16 waves = 32 waves/CU. R12 (16 w/CU) == R13 (32 w/CU) at
// ~371 us proves we are VALU-ISSUE-bound, so this round only removes
// instructions: read-addr set == write-addr set -> 4 SWZ per step, not 32.
// NOTE v_pk_fma_f32 is NOT a win on CDNA4 (fp32 peak 157.3 TF == unpacked
// rate; R14 regressed) — keep scalar v_fmac with SGPR M operand.
__global__ __launch_bounds__(1024, 8)
void peps_amp_kernel(const int* __restrict__ X, const float* __restrict__ Tm,
                     float* __restrict__ out)
{
    __shared__ float W[16384];   // 65536 B exactly (4^7 fixed-slot state)

    const int b = blockIdx.x;
    const int t = threadIdx.x;   // == this thread's spectator index m
    const int* xrow = X + b * NSITE;

    // PHYS=2: pack the 36 spins into one scalar 64-bit mask (SGPR-resident
    // so every Tm address below is provably wave-uniform).
    unsigned long long sm = 0ull;
    const int4* xp = (const int4*)xrow;
    #pragma unroll
    for (int k = 0; k < 9; ++k) {
        int4 v = xp[k];
        sm |= ((unsigned long long)(v.x & 1)) << (4 * k + 0);
        sm |= ((unsigned long long)(v.y & 1)) << (4 * k + 1);
        sm |= ((unsigned long long)(v.z & 1)) << (4 * k + 2);
        sm |= ((unsigned long long)(v.w & 1)) << (4 * k + 3);
    }
    {
        unsigned lo = __builtin_amdgcn_readfirstlane((int)(sm & 0xffffffffull));
        unsigned hi = __builtin_amdgcn_readfirstlane((int)(sm >> 32));
        sm = ((unsigned long long)hi << 32) | lo;
    }

    if (t == 0) W[0] = 1.0f;     // seed (SWZ(0)==0); covered by step-0 barrier

    int step = 0;
    for (int row = 0; row < NROW; ++row) {
        const int xs = (row == 0) ? 1 : 4;          // up-bond size
        const int zs = (row == NROW - 1) ? 1 : 4;   // down-bond size
        for (int c = 0; c < NCOL; ++c, ++step) {
            const int gin  = (c == 0) ? 1 : 4;
            const int gout = (c == NCOL - 1) ? 1 : 4;
            const int lowb  = (zs == 4) ? 2 * c : 0;
            const int highb = (xs == 4) ? 2 * (5 - c) : 0;
            const int scount = 1 << (lowb + highb);
            const int p4c = 1 << (2 * c);
            const int lowmask = (1 << lowb) - 1;
            const int mr0 = ((t >> lowb) << (2 * c + 2)) | (t & lowmask);
            const bool act = (t < scount);

            // uniform scalar: spin bit + M base for this step (SMEM pointer)
            const int spin = (int)((sm >> step) & 1ull);
            const fcp Msf = (fcp)(unsigned long long)
                (const void*)(Tm + (size_t)(step * 2 + spin) * 256);

            __syncthreads();     // the ONLY barrier per step

            // ---- shared read/write LDS addresses (x and z span slot c) ----
            int A[4];
            if (c == 0) {
                A[0] = SWZ(4 * t);          // aligned quad base (low digit)
            } else {
                #pragma unroll
                for (int d = 0; d < 4; ++d) A[d] = SWZ(d * p4c + mr0);
            }

            // ---- read phase (divergent, thread-private addresses) ----
            float in[16];
            if (act) {
                if (c == 0) {
                    #pragma unroll
                    for (int g = 0; g < 4; ++g) if (g < gin) {
                        float4 r0 = *(const float4*)&W[A[0] + g * 4096];
                        in[g*4+0]=r0.x; in[g*4+1]=r0.y;
                        in[g*4+2]=r0.z; in[g*4+3]=r0.w;
                    }
                } else {
                    #pragma unroll
                    for (int g = 0; g < 4; ++g) if (g < gin) {
                        #pragma unroll
                        for (int x = 0; x < 4; ++x) if (x < xs) {
                            in[g*4+x] = W[A[x] + g * 4096];
                        }
                    }
                }
            }

            // ---- compute + write; M via s_load (uniform, invariant) ----
            #pragma unroll
            for (int gp = 0; gp < 4; ++gp) if (gp < gout) {
                float a[4];
                #pragma unroll
                for (int z = 0; z < 4; ++z) if (z < zs) {
                    const int mb = (gp * 4 + z) * 16;
                    float mm[16];
                    #pragma unroll
                    for (int j = 0; j < 4; ++j) mm[j] = Msf[mb + j];
                    if (gin == 4) {
                        #pragma unroll
                        for (int j = 4; j < 16; ++j) mm[j] = Msf[mb + j];
                    }
                    float s0 = 0.f;
                    if (act) {
                        #pragma unroll
                        for (int g = 0; g < 4; ++g) if (g < gin) {
                            s0 += mm[g*4+0] * in[g*4+0];
                            if (xs == 4) {
                                s0 += mm[g*4+1] * in[g*4+1];
                                s0 += mm[g*4+2] * in[g*4+2];
                                s0 += mm[g*4+3] * in[g*4+3];
                            }
                        }
                    }
                    a[z] = s0;
                    if (act) {
                        if (c != 0 && zs == 4) {
                            W[A[z] + gp * 4096] = s0;
                        } else if (zs == 1) {
                            W[A[0] + gp * 4096] = s0;
                        }
                    }
                }
                if (c == 0 && zs == 4 && act) {
                    *(float4*)&W[A[0] + gp * 4096] =
                        make_float4(a[0], a[1], a[2], a[3]);
                }
            }
        }
    }
    __syncthreads();
    // after (5,5): only g'=0, z=0, m=0 live -> the amplitude sits at W[0]
    if (t == 0) out[b] = W[0];
}

extern "C" void kernel_launch(void* const* d_in, const int* in_sizes, int n_in,
                              void* d_out, int out_size, void* d_ws, size_t ws_size,
                              hipStream_t stream) {
    const int*   X  = (const int*)d_in[0];     // x: [1024, 36] int32
    const float* Tg = (const float*)d_in[1];   // T: [6,6,2,4,4,4,4] fp32
    float* out = (float*)d_out;                // reference output: float32
    float* Tm  = (float*)d_ws;                 // 73,728 B scratch
    (void)in_sizes; (void)n_in; (void)ws_size; (void)out_size;
    peps_reorder_kernel<<<dim3(72), dim3(256), 0, stream>>>(Tg, Tm);
    peps_amp_kernel<<<dim3(BATCH), dim3(1024), 0, stream>>>(X, Tm, out);
}

// Round 16
// 234.026 us; speedup vs baseline: 1.7736x; 1.6180x over previous
//
#include <hip/hip_runtime.h>

#define NROW 6
#define NCOL 6
#define BATCH 1024
#define NSITE 36

// LDS bank-conflict swizzle: XOR dword-addr bits [4:2] with bits [7:5].
// Preserves bits [1:0]; constant within any aligned 4-dword window; SWZ(0)==0.
// Note SWZ(g*4096 + low) == g*4096 + SWZ(low) for low < 4096.
__device__ __forceinline__ int SWZ(int a) { return a ^ (((a >> 5) & 7) << 2); }

// Wave-uniform scalar-memory pointer: address_space(4) = AMDGPU constant.
// Scalar float loads at uniform offsets merge into s_load_dwordx4/x16 (SMEM
// pipe, one fetch per wave) — R12 proved this path (534 -> 372 us). Scalar
// loads are exec-independent, so they may sit inside the act-guard.
typedef const float __attribute__((address_space(4))) * fcp;

// Pre-transpose T[site][spin][u=x][r=gp][d=z][l=g] into
// Tm[(site*2+spin)*256 + (gp*4+z)*16 + (g*4+x)]  (73,728 B in d_ws).
__global__ void peps_reorder_kernel(const float* __restrict__ T,
                                    float* __restrict__ Tm)
{
    int idx = blockIdx.x * 256 + threadIdx.x;   // [0, 18432)
    if (idx >= NSITE * 2 * 256) return;
    int i  = idx & 15;          // i = g*4 + x
    int o  = (idx >> 4) & 15;   // o = gp*4 + z
    int sp = (idx >> 8) & 1;
    int st = idx >> 9;
    int g = i >> 2, x = i & 3, gp = o >> 2, z = o & 3;
    Tm[idx] = T[st * 512 + sp * 256 + x * 64 + gp * 16 + z * 4 + g];
}

// One step body, fully specialized: compile-time bond sizes -> straight-line
// code with EXACTLY ONE divergent branch (act) and zero interior branches.
// R15's binder theory: 16 exec save/restores + ~64 uniform branch islands
// per step bloated VALU issue ~4x over the FMA wall.
template<int GIN, int GOUT, int XS, int ZS, bool C0>
__device__ __forceinline__ void do_step(float* __restrict__ W, const fcp Msf,
                                        const int* __restrict__ A, bool act)
{
    if (act) {
        // ---- read phase (thread-private swizzled addresses) ----
        float in[16];
        if (C0) {
            #pragma unroll
            for (int g = 0; g < GIN; ++g) {
                float4 r = *(const float4*)&W[A[0] + g * 4096];
                in[g*4+0] = r.x; in[g*4+1] = r.y;
                in[g*4+2] = r.z; in[g*4+3] = r.w;
            }
        } else {
            #pragma unroll
            for (int g = 0; g < GIN; ++g)
                #pragma unroll
                for (int x = 0; x < XS; ++x)
                    in[g*4+x] = W[A[x] + g * 4096];
        }
        // ---- compute + write (in-place; same addresses) ----
        #pragma unroll
        for (int gp = 0; gp < GOUT; ++gp) {
            float a[ZS];
            #pragma unroll
            for (int z = 0; z < ZS; ++z) {
                const int mb = (gp * 4 + z) * 16;
                float s = 0.f;
                #pragma unroll
                for (int g = 0; g < GIN; ++g)
                    #pragma unroll
                    for (int x = 0; x < XS; ++x)
                        s += Msf[mb + g * 4 + x] * in[g*4+x];
                a[z] = s;
            }
            if (C0 && ZS == 4) {
                *(float4*)&W[A[0] + gp * 4096] =
                    make_float4(a[0], a[1], a[2], a[3]);
            } else if (ZS == 4) {
                #pragma unroll
                for (int z = 0; z < 4; ++z) W[A[z] + gp * 4096] = a[z];
            } else {
                W[A[0] + gp * 4096] = a[0];
            }
        }
    }
}

// Fixed-slot in-place contraction (verified R8..R15 algebra): state index =
// g*4096 + sum_j slot_j*4^j; step (row,c) reads up-bond x from slot c and
// writes down-bond z back into the same slot. ONE barrier/step. State in LDS
// (64 KB, swizzled). M via AS(4) s_load. 1024 threads: 2 blocks/CU x 16
// waves = 32 waves/CU.
__global__ __launch_bounds__(1024, 8)
void peps_amp_kernel(const int* __restrict__ X, const float* __restrict__ Tm,
                     float* __restrict__ out)
{
    __shared__ float W[16384];   // 65536 B exactly (4^7 fixed-slot state)

    const int b = blockIdx.x;
    const int t = threadIdx.x;   // == this thread's spectator index m
    const int* xrow = X + b * NSITE;

    // PHYS=2: pack the 36 spins into one scalar 64-bit mask (SGPR-resident
    // so every Tm address below is provably wave-uniform).
    unsigned long long sm = 0ull;
    const int4* xp = (const int4*)xrow;
    #pragma unroll
    for (int k = 0; k < 9; ++k) {
        int4 v = xp[k];
        sm |= ((unsigned long long)(v.x & 1)) << (4 * k + 0);
        sm |= ((unsigned long long)(v.y & 1)) << (4 * k + 1);
        sm |= ((unsigned long long)(v.z & 1)) << (4 * k + 2);
        sm |= ((unsigned long long)(v.w & 1)) << (4 * k + 3);
    }
    {
        unsigned lo = __builtin_amdgcn_readfirstlane((int)(sm & 0xffffffffull));
        unsigned hi = __builtin_amdgcn_readfirstlane((int)(sm >> 32));
        sm = ((unsigned long long)hi << 32) | lo;
    }

    if (t == 0) W[0] = 1.0f;     // seed (SWZ(0)==0); covered by step-0 barrier

    int step = 0;
    for (int row = 0; row < NROW; ++row) {
        const int xs = (row == 0) ? 1 : 4;          // up-bond size
        const int zs = (row == NROW - 1) ? 1 : 4;   // down-bond size
        for (int c = 0; c < NCOL; ++c, ++step) {
            const int lowb  = (zs == 4) ? 2 * c : 0;
            const int highb = (xs == 4) ? 2 * (5 - c) : 0;
            const int scount = 1 << (lowb + highb);
            const int p4c = 1 << (2 * c);
            const int lowmask = (1 << lowb) - 1;
            const int mr0 = ((t >> lowb) << (2 * c + 2)) | (t & lowmask);
            const bool act = (t < scount);

            // uniform scalar: spin bit + M base for this step (SMEM pointer)
            const int spin = (int)((sm >> step) & 1ull);
            const fcp Msf = (fcp)(unsigned long long)
                (const void*)(Tm + (size_t)(step * 2 + spin) * 256);

            __syncthreads();     // the ONLY barrier per step

            // shared read/write LDS addresses (x and z both span slot c)
            int A[4];
            if (c == 0) {
                A[0] = SWZ(4 * t);           // aligned quad base (low digit)
                A[1] = A[2] = A[3] = A[0];
            } else {
                #pragma unroll
                for (int d = 0; d < 4; ++d) A[d] = SWZ(d * p4c + mr0);
            }

            // uniform 3x3 dispatch to branch-free specialized bodies
            if (row == 0) {
                if (c == 0)              do_step<1,4,1,4,true >(W, Msf, A, act);
                else if (c < NCOL - 1)   do_step<4,4,1,4,false>(W, Msf, A, act);
                else                     do_step<4,1,1,4,false>(W, Msf, A, act);
            } else if (row < NROW - 1) {
                if (c == 0)              do_step<1,4,4,4,true >(W, Msf, A, act);
                else if (c < NCOL - 1)   do_step<4,4,4,4,false>(W, Msf, A, act);
                else                     do_step<4,1,4,4,false>(W, Msf, A, act);
            } else {
                if (c == 0)              do_step<1,4,4,1,true >(W, Msf, A, act);
                else if (c < NCOL - 1)   do_step<4,4,4,1,false>(W, Msf, A, act);
                else                     do_step<4,1,4,1,false>(W, Msf, A, act);
            }
        }
    }
    __syncthreads();
    // after (5,5): only g'=0, z=0, m=0 live -> the amplitude sits at W[0]
    if (t == 0) out[b] = W[0];
}

extern "C" void kernel_launch(void* const* d_in, const int* in_sizes, int n_in,
                              void* d_out, int out_size, void* d_ws, size_t ws_size,
                              hipStream_t stream) {
    const int*   X  = (const int*)d_in[0];     // x: [1024, 36] int32
    const float* Tg = (const float*)d_in[1];   // T: [6,6,2,4,4,4,4] fp32
    float* out = (float*)d_out;                // reference output: float32
    float* Tm  = (float*)d_ws;                 // 73,728 B scratch
    (void)in_sizes; (void)n_in; (void)ws_size; (void)out_size;
    peps_reorder_kernel<<<dim3(72), dim3(256), 0, stream>>>(Tg, Tm);
    peps_amp_kernel<<<dim3(BATCH), dim3(1024), 0, stream>>>(X, Tm, out);
}

// Round 17
// 199.822 us; speedup vs baseline: 2.0772x; 1.1712x over previous
//
#include <hip/hip_runtime.h>

#define NROW 6
#define NCOL 6
#define BATCH 1024
#define NSITE 36

// LDS bank-conflict swizzle: XOR dword-addr bits [4:2] with bits [7:5].
// Preserves bits [1:0]; constant within any aligned 4-dword window; SWZ(0)==0.
__device__ __forceinline__ int SWZ(int a) { return a ^ (((a >> 5) & 7) << 2); }

// Wave-uniform scalar-memory pointer: address_space(4) = AMDGPU constant.
// Scalar float loads at uniform offsets merge into s_load_dwordx4/x16 (SMEM
// pipe, one fetch per wave) — R12 proved this path (534 -> 372 us).
typedef const float __attribute__((address_space(4))) * fcp;

// Pre-transpose T[site][spin][u=x][r=gp][d=z][l=g] into
// Tm[(site*2+spin)*256 + (gp*4+z)*16 + (g*4+x)]  (73,728 B in d_ws).
__global__ void peps_reorder_kernel(const float* __restrict__ T,
                                    float* __restrict__ Tm)
{
    int idx = blockIdx.x * 256 + threadIdx.x;   // [0, 18432)
    if (idx >= NSITE * 2 * 256) return;
    int i  = idx & 15;          // i = g*4 + x
    int o  = (idx >> 4) & 15;   // o = gp*4 + z
    int sp = (idx >> 8) & 1;
    int st = idx >> 9;
    int g = i >> 2, x = i & 3, gp = o >> 2, z = o & 3;
    Tm[idx] = T[st * 512 + sp * 256 + x * 64 + gp * 16 + z * 4 + g];
}

// One step body, 4 SPECTATORS PER THREAD (u = 4t..4t+3), fully specialized,
// one divergent branch. Spectator quads are LDS-contiguous for all ZS==4 and
// C0 steps -> all state traffic is ds_read_b128/ds_write_b128 (4x fewer LDS
// insts than R16's b32-per-spectator), addresses/s_loads amortized 4x, and
// 4 independent FMA chains (ILP). R16's VGPR=16 showed in[] was not being
// register-cached; in_s[4][16] under __launch_bounds__(256,2) (cap 256) is.
template<int GIN, int GOUT, int XS, int ZS, bool C0>
__device__ __forceinline__ void do_step4(float* __restrict__ W, const fcp Msf,
                                         const int* __restrict__ A, int p4c,
                                         bool act)
{
    if (!act) return;
    float in_s[4][16];           // [spectator][g*4+x]
    // ---- read phase ----
    if (C0) {                    // GIN==1; x (or z) is the low address digit
        if (XS == 4) {
            #pragma unroll
            for (int i = 0; i < 4; ++i) {
                float4 q = *(const float4*)&W[A[i]];
                in_s[i][0] = q.x; in_s[i][1] = q.y;
                in_s[i][2] = q.z; in_s[i][3] = q.w;
            }
        } else {
            #pragma unroll
            for (int i = 0; i < 4; ++i) in_s[i][0] = W[A[i]];
        }
    } else if (ZS == 4) {        // spectator quad contiguous at A[x]
        #pragma unroll
        for (int g = 0; g < GIN; ++g)
            #pragma unroll
            for (int x = 0; x < XS; ++x) {
                float4 q = *(const float4*)&W[A[x] + g * 4096];
                in_s[0][g*4+x] = q.x; in_s[1][g*4+x] = q.y;
                in_s[2][g*4+x] = q.z; in_s[3][g*4+x] = q.w;
            }
    } else {                     // row5 c>=1: scattered scalars (tiny work)
        #pragma unroll
        for (int g = 0; g < GIN; ++g)
            #pragma unroll
            for (int x = 0; x < XS; ++x)
                #pragma unroll
                for (int i = 0; i < 4; ++i)
                    in_s[i][g*4+x] = W[SWZ(x * p4c + A[i]) + g * 4096];
    }
    // ---- compute + write (in-place; same address set) ----
    #pragma unroll
    for (int gp = 0; gp < GOUT; ++gp) {
        float a[ZS][4];
        #pragma unroll
        for (int z = 0; z < ZS; ++z) {
            const int mb = (gp * 4 + z) * 16;
            #pragma unroll
            for (int i = 0; i < 4; ++i) a[z][i] = 0.f;
            #pragma unroll
            for (int g = 0; g < GIN; ++g)
                #pragma unroll
                for (int x = 0; x < XS; ++x) {
                    const float m = Msf[mb + g * 4 + x];
                    #pragma unroll
                    for (int i = 0; i < 4; ++i)
                        a[z][i] += m * in_s[i][g*4+x];
                }
        }
        if (C0 && ZS == 4) {
            #pragma unroll
            for (int i = 0; i < 4; ++i)
                *(float4*)&W[A[i] + gp * 4096] =
                    make_float4(a[0][i], a[1][i], a[2][i], a[3][i]);
        } else if (ZS == 4) {
            #pragma unroll
            for (int z = 0; z < 4; ++z)
                *(float4*)&W[A[z] + gp * 4096] =
                    make_float4(a[z][0], a[z][1], a[z][2], a[z][3]);
        } else if (C0) {         // row5 c0: z collapses, base address
            #pragma unroll
            for (int i = 0; i < 4; ++i) W[A[i] + gp * 4096] = a[0][i];
        } else {                 // row5 c>=1
            #pragma unroll
            for (int i = 0; i < 4; ++i) W[SWZ(A[i]) + gp * 4096] = a[0][i];
        }
    }
}

// Fixed-slot in-place contraction (verified R8..R16 algebra): state index =
// g*4096 + sum_j slot_j*4^j; step (row,c) reads up-bond x from slot c and
// writes down-bond z back into the same slot. ONE barrier/step. State in LDS
// (64 KB, swizzled). scount=1 steps: (0,0)'s stray spectator writes land in
// W[4..15](+gp*4096), fully overwritten by step (0,1) before (0,2) reads
// them; (5,5) is last (only W[0] read). 256 threads x 4 spectators; 2
// blocks/CU (LDS-bound), 8 waves/CU — R12==R13 showed we're issue-bound.
__global__ __launch_bounds__(256, 2)
void peps_amp_kernel(const int* __restrict__ X, const float* __restrict__ Tm,
                     float* __restrict__ out)
{
    __shared__ float W[16384];   // 65536 B exactly (4^7 fixed-slot state)

    const int b = blockIdx.x;
    const int t = threadIdx.x;
    const int u0 = 4 * t;        // this thread's spectators: u0..u0+3
    const int* xrow = X + b * NSITE;

    // PHYS=2: pack the 36 spins into one scalar 64-bit mask (SGPR-resident
    // so every Tm address below is provably wave-uniform).
    unsigned long long sm = 0ull;
    const int4* xp = (const int4*)xrow;
    #pragma unroll
    for (int k = 0; k < 9; ++k) {
        int4 v = xp[k];
        sm |= ((unsigned long long)(v.x & 1)) << (4 * k + 0);
        sm |= ((unsigned long long)(v.y & 1)) << (4 * k + 1);
        sm |= ((unsigned long long)(v.z & 1)) << (4 * k + 2);
        sm |= ((unsigned long long)(v.w & 1)) << (4 * k + 3);
    }
    {
        unsigned lo = __builtin_amdgcn_readfirstlane((int)(sm & 0xffffffffull));
        unsigned hi = __builtin_amdgcn_readfirstlane((int)(sm >> 32));
        sm = ((unsigned long long)hi << 32) | lo;
    }

    if (t == 0) W[0] = 1.0f;     // seed (SWZ(0)==0); covered by step-0 barrier

    int step = 0;
    for (int row = 0; row < NROW; ++row) {
        const int xs = (row == 0) ? 1 : 4;          // up-bond size
        const int zs = (row == NROW - 1) ? 1 : 4;   // down-bond size
        for (int c = 0; c < NCOL; ++c, ++step) {
            const int lowb  = (zs == 4) ? 2 * c : 0;
            const int highb = (xs == 4) ? 2 * (5 - c) : 0;
            const int scount = 1 << (lowb + highb);
            const int p4c = 1 << (2 * c);
            const int lowmask = (1 << lowb) - 1;
            const bool act = (u0 < scount);

            // uniform scalar: spin bit + M base for this step (SMEM pointer)
            const int spin = (int)((sm >> step) & 1ull);
            const fcp Msf = (fcp)(unsigned long long)
                (const void*)(Tm + (size_t)(step * 2 + spin) * 256);

            __syncthreads();     // the ONLY barrier per step

            // per-thread LDS addresses (quad-aligned where vectorized)
            int A[4];
            if (c == 0) {
                #pragma unroll
                for (int i = 0; i < 4; ++i) A[i] = SWZ(16 * t + 4 * i);
            } else if (zs == 4) {
                const int mr0 = ((u0 >> lowb) << (2 * c + 2)) | (u0 & lowmask);
                #pragma unroll
                for (int d = 0; d < 4; ++d) A[d] = SWZ(d * p4c + mr0);
            } else {             // row5 c>=1: per-spectator bases, unswizzled
                #pragma unroll
                for (int i = 0; i < 4; ++i) A[i] = (u0 + i) << (2 * c + 2);
            }

            // uniform 3x3 dispatch to branch-free specialized bodies
            if (row == 0) {
                if (c == 0)            do_step4<1,4,1,4,true >(W, Msf, A, p4c, act);
                else if (c < NCOL - 1) do_step4<4,4,1,4,false>(W, Msf, A, p4c, act);
                else                   do_step4<4,1,1,4,false>(W, Msf, A, p4c, act);
            } else if (row < NROW - 1) {
                if (c == 0)            do_step4<1,4,4,4,true >(W, Msf, A, p4c, act);
                else if (c < NCOL - 1) do_step4<4,4,4,4,false>(W, Msf, A, p4c, act);
                else                   do_step4<4,1,4,4,false>(W, Msf, A, p4c, act);
            } else {
                if (c == 0)            do_step4<1,4,4,1,true >(W, Msf, A, p4c, act);
                else if (c < NCOL - 1) do_step4<4,4,4,1,false>(W, Msf, A, p4c, act);
                else                   do_step4<4,1,4,1,false>(W, Msf, A, p4c, act);
            }
        }
    }
    __syncthreads();
    // after (5,5): only g'=0, z=0, u=0 live -> the amplitude sits at W[0]
    if (t == 0) out[b] = W[0];
}

extern "C" void kernel_launch(void* const* d_in, const int* in_sizes, int n_in,
                              void* d_out, int out_size, void* d_ws, size_t ws_size,
                              hipStream_t stream) {
    const int*   X  = (const int*)d_in[0];     // x: [1024, 36] int32
    const float* Tg = (const float*)d_in[1];   // T: [6,6,2,4,4,4,4] fp32
    float* out = (float*)d_out;                // reference output: float32
    float* Tm  = (float*)d_ws;                 // 73,728 B scratch
    (void)in_sizes; (void)n_in; (void)ws_size; (void)out_size;
    peps_reorder_kernel<<<dim3(72), dim3(256), 0, stream>>>(Tg, Tm);
    peps_amp_kernel<<<dim3(BATCH), dim3(256), 0, stream>>>(X, Tm, out);
}